// Round 4
// baseline (623.966 us; speedup 1.0000x reference)
//
#include <hip/hip_runtime.h>
#include <math.h>

#define NGRAPH 1024
#define NN     256
#define NE     2048
#define EMB    39
#define HD     64
#define STRIDE 65     // bank = (row + lane) % 32 -> exactly 2-way alias on row ops = free (m136)
#define NT     1024   // 16 waves; 2 blocks/CU (LDS 80.5KB) -> 32 waves/CU = 100% occupancy cap
#define K1 205
#define K2 164
#define K3 132

// LDS (4-byte units unless noted):
//  feat    16640 f  one buffer: x -> h (in place) -> pooled rows
//  scratch  2048 f  union: epk u16[2048] (B1-B4) | col u8[2048] @+4096B (B4-B5)
//                          ipart i32[1024] (B8-B9) | red f[2048] (B11-B12)
//  cnt 260 i ; cur 256 i ; dinv 256 f ; score 256 f (16B-aligned) ; feats 128 f
//  pn 64 f ; mlp1 64 f ; mlp2 32 f ; nodemap 256 s16
//  total = 80528 B -> 2 blocks/CU (161056 <= 163840)
#define SMEM_BYTES 80528

struct Lds {
    float* feat; float* scratch; int* cnt; int* cur; float* dinv; float* score;
    float* feats; float* pn; float* mlp1; float* mlp2; short* nodemap;
};

template<int FIN>
__device__ __forceinline__ void layer_body(
    const Lds& S, const int* __restrict__ eb,
    const float* __restrict__ W, const float* __restrict__ bvec,
    const float* __restrict__ pvec, int n, int kkeep, int tid)
{
    unsigned short* epk   = (unsigned short*)S.scratch;          // 4096 B
    unsigned char*  col   = (unsigned char*)(S.scratch + 1024);  // 2048 B, disjoint from epk
    int*            ipart = (int*)S.scratch;                     // 4096 B (epk dead)
    float*          red   = S.scratch;                           // 8192 B (col/ipart dead)
    const int lane = tid & 63;
    const int w    = tid >> 6;       // 0..15

    // B0: zero counts; wave0: pn = p/||p||
    if (tid < 257) S.cnt[tid] = 0;
    if (tid < 64) {
        float pv = pvec[tid];
        float s2 = pv * pv;
        #pragma unroll
        for (int off = 32; off >= 1; off >>= 1) s2 += __shfl_xor(s2, off, 64);
        S.pn[tid] = pv * rsqrtf(s2);
    }
    __syncthreads();

    // B1: remap orig edges via cumulative nodemap; int-atomic in-degree count
    for (int e = tid; e < NE; e += NT) {
        int s0 = eb[e];
        int d0 = eb[NE + e];
        int s = S.nodemap[s0];
        int d = S.nodemap[d0];
        unsigned short pk = 0xFFFFu;
        if ((s | d) >= 0) {
            pk = (unsigned short)(s | (d << 8));
            atomicAdd(&S.cnt[d], 1);          // native ds_add_u32
        }
        epk[e] = pk;
    }
    __syncthreads();

    // B2: exclusive scan cnt[0..255] -> offsets (single wave)
    if (tid < 64) {
        int base = tid * 4;
        int c0 = S.cnt[base], c1 = S.cnt[base + 1], c2 = S.cnt[base + 2], c3 = S.cnt[base + 3];
        int s4 = c0 + c1 + c2 + c3;
        int x = s4;
        #pragma unroll
        for (int off = 1; off < 64; off <<= 1) {
            int t = __shfl_up(x, off, 64);
            if (tid >= off) x += t;
        }
        int e0 = x - s4;
        S.cnt[base]     = e0;
        S.cnt[base + 1] = e0 + c0;
        S.cnt[base + 2] = e0 + c0 + c1;
        S.cnt[base + 3] = e0 + c0 + c1 + c2;
        if (tid == 63) S.cnt[256] = x;
    }
    __syncthreads();

    // B3: cursors = offsets; dinv = rsqrt(1+indeg)
    if (tid < 256) {
        int o0 = S.cnt[tid], o1 = S.cnt[tid + 1];
        S.cur[tid]  = o0;
        S.dinv[tid] = rsqrtf((float)(1 + o1 - o0));
    }
    __syncthreads();

    // B4: CSR fill (int-atomic cursors) + matmul h = x@W into regs (4 thr/node x 16 out)
    for (int e = tid; e < NE; e += NT) {
        unsigned pk = epk[e];
        if (pk != 0xFFFFu) {
            int d = pk >> 8;
            int pos = atomicAdd(&S.cur[d], 1);
            col[pos] = (unsigned char)(pk & 0xFFu);
        }
    }
    float h[16];
    {
        const int nodeM = tid & 255;
        const int q4 = __builtin_amdgcn_readfirstlane(tid >> 8);  // wave-uniform -> scalar W loads
        if (nodeM < n) {
            #pragma unroll
            for (int j = 0; j < 16; j++) h[j] = 0.f;
            const float* Wp   = W + q4 * 16;
            const float* xrow = S.feat + nodeM * STRIDE;
            for (int k = 0; k < FIN; k++) {
                float xv = xrow[k];
                #pragma unroll
                for (int j = 0; j < 16; j++) h[j] = fmaf(xv, Wp[k * HD + j], h[j]);
            }
        }
        __syncthreads();   // all x reads done before h overwrites (in-place)
        if (nodeM < n) {
            float* hrow = S.feat + nodeM * STRIDE + q4 * 16;
            #pragma unroll
            for (int j = 0; j < 16; j++) hrow[j] = h[j];
        }
    }
    __syncthreads();

    // B5: gather, wave-per-node, lane=feature: conflict-free, divergence-free
    float outv[16], tanhv[16];
    {
        const float bl = bvec[lane];
        const float pl = S.pn[lane];
        #pragma unroll
        for (int i = 0; i < 16; i++) {
            int node = w * 16 + i;
            if (node < n) {
                int o0 = S.cnt[node], o1 = S.cnt[node + 1];   // broadcast reads
                float acc = 0.f;
                #pragma unroll 2
                for (int e = o0; e < o1; e++) {
                    int s = col[e];                            // broadcast
                    acc = fmaf(S.dinv[s], S.feat[s * STRIDE + lane], acc);
                }
                float dvd = S.dinv[node];
                float hv  = S.feat[node * STRIDE + lane];
                float o = fmaxf(fmaf(dvd, acc, fmaf(hv, dvd * dvd, bl)), 0.f);
                outv[i] = o;
                float sc = o * pl;
                #pragma unroll
                for (int off = 32; off >= 1; off >>= 1) sc += __shfl_xor(sc, off, 64);
                float tv = tanhf(sc);
                tanhv[i] = tv;
                if (lane == 0) S.score[node] = tv;
            } else {
                outv[i] = 0.f; tanhv[i] = 0.f;
                if (lane == 0) S.score[node] = -3.4e38f;       // -inf pad: never selected
            }
        }
    }
    __syncthreads();

    // B8: rank by counting, 4 thr/node, float4 broadcast reads, fixed 16 iters
    {
        const int nodeR = tid & 255;
        const int q = tid >> 8;
        float si = S.score[nodeR];
        const float4* s4 = (const float4*)(S.score + q * 64);
        int c = 0;
        #pragma unroll
        for (int t = 0; t < 16; t++) {
            float4 v = s4[t];
            int j = q * 64 + t * 4;
            c += (v.x > si) || (v.x == si && (j    ) < nodeR);
            c += (v.y > si) || (v.y == si && (j + 1) < nodeR);
            c += (v.z > si) || (v.z == si && (j + 2) < nodeR);
            c += (v.w > si) || (v.w == si && (j + 3) < nodeR);
        }
        ipart[tid] = c;
    }
    __syncthreads();

    // B9: rank -> cur (cursors dead)
    if (tid < 256) S.cur[tid] = ipart[tid] + ipart[tid + 256] + ipart[tid + 512] + ipart[tid + 768];
    __syncthreads();

    // B10: compose nodemap; pooled rows + readout partials straight from regs
    if (tid < 256) {
        int m = S.nodemap[tid];
        if (m >= 0) {
            int r = S.cur[m];
            S.nodemap[tid] = (short)((r < kkeep) ? r : -1);
        }
    }
    {
        float mx = -3.4e38f, sm = 0.f;
        #pragma unroll
        for (int i = 0; i < 16; i++) {
            int node = w * 16 + i;
            int r = S.cur[node];                 // wave-uniform
            if (node < n && r < kkeep) {
                float v = outv[i] * tanhv[i];
                S.feat[r * STRIDE + lane] = v;
                mx = fmaxf(mx, v);
                sm += v;
            }
        }
        red[w * 64 + lane]        = mx;
        red[1024 + w * 64 + lane] = sm;
    }
    __syncthreads();

    // B12: combine 16 wave-partials into feats
    if (tid < 64) {
        float mx = red[tid], sm = red[1024 + tid];
        #pragma unroll
        for (int q = 1; q < 16; q++) {
            mx = fmaxf(mx, red[q * 64 + tid]);
            sm += red[1024 + q * 64 + tid];
        }
        S.feats[tid]      += mx;
        S.feats[64 + tid] += sm / (float)kkeep;
    }
    __syncthreads();
}

__global__ __launch_bounds__(NT, 8) void gnn_pool_kernel(
    const float* __restrict__ gx, const int* __restrict__ gedge,
    const float* __restrict__ W1, const float* __restrict__ b1, const float* __restrict__ p1,
    const float* __restrict__ W2, const float* __restrict__ b2, const float* __restrict__ p2,
    const float* __restrict__ W3, const float* __restrict__ b3, const float* __restrict__ p3,
    const float* __restrict__ lW1, const float* __restrict__ lb1,
    const float* __restrict__ lW2, const float* __restrict__ lb2,
    const float* __restrict__ lW3, const float* __restrict__ lb3,
    float* __restrict__ gout)
{
    extern __shared__ __align__(16) char smem_raw[];
    Lds S;
    S.feat    = (float*)smem_raw;                 // 16640
    S.scratch = S.feat + NN * STRIDE;             // 2048
    S.cnt     = (int*)(S.scratch + 2048);         // 260
    S.cur     = S.cnt + 260;                      // 256
    S.dinv    = (float*)(S.cur + 256);            // 256
    S.score   = S.dinv + 256;                     // 256 (byte off 77840, 16B-aligned)
    S.feats   = S.score + 256;                    // 128
    S.pn      = S.feats + 128;                    // 64
    S.mlp1    = S.pn + 64;                        // 64
    S.mlp2    = S.mlp1 + 64;                      // 32
    S.nodemap = (short*)(S.mlp2 + 32);            // 256 s16

    const int tid = threadIdx.x;
    const int b   = blockIdx.x;
    const int* eb = gedge + (size_t)b * 2 * NE;

    {
        const float* xb = gx + (size_t)b * NN * EMB;
        for (int i = tid; i < NN * EMB; i += NT) {
            S.feat[(i / EMB) * STRIDE + (i % EMB)] = xb[i];
        }
        if (tid < NN) S.nodemap[tid] = (short)tid;
        if (tid < 2 * HD) S.feats[tid] = 0.f;
    }
    __syncthreads();

    layer_body<EMB>(S, eb, W1, b1, p1, NN, K1, tid);
    layer_body<HD >(S, eb, W2, b2, p2, K1, K2, tid);
    layer_body<HD >(S, eb, W3, b3, p3, K2, K3, tid);

    // final MLP: 128 -> 64 -> 32 -> 1, sigmoid
    if (tid < 64) {
        float a = lb1[tid];
        for (int i = 0; i < 2 * HD; i++) a = fmaf(S.feats[i], lW1[i * 64 + tid], a);
        S.mlp1[tid] = fmaxf(a, 0.f);
    }
    __syncthreads();
    if (tid < 32) {
        float a = lb2[tid];
        for (int i = 0; i < 64; i++) a = fmaf(S.mlp1[i], lW2[i * 32 + tid], a);
        S.mlp2[tid] = fmaxf(a, 0.f);
    }
    __syncthreads();
    if (tid == 0) {
        float a = lb3[0];
        for (int i = 0; i < 32; i++) a = fmaf(S.mlp2[i], lW3[i], a);
        gout[b] = 1.0f / (1.0f + expf(-a));
    }
}

extern "C" void kernel_launch(void* const* d_in, const int* in_sizes, int n_in,
                              void* d_out, int out_size, void* d_ws, size_t ws_size,
                              hipStream_t stream) {
    const float* gx    = (const float*)d_in[0];
    const int*   gedge = (const int*)d_in[1];
    const float* W1 = (const float*)d_in[2];
    const float* b1 = (const float*)d_in[3];
    const float* p1 = (const float*)d_in[4];
    const float* W2 = (const float*)d_in[5];
    const float* b2 = (const float*)d_in[6];
    const float* p2 = (const float*)d_in[7];
    const float* W3 = (const float*)d_in[8];
    const float* b3 = (const float*)d_in[9];
    const float* p3 = (const float*)d_in[10];
    const float* lW1 = (const float*)d_in[11];
    const float* lb1 = (const float*)d_in[12];
    const float* lW2 = (const float*)d_in[13];
    const float* lb2 = (const float*)d_in[14];
    const float* lW3 = (const float*)d_in[15];
    const float* lb3 = (const float*)d_in[16];
    float* gout = (float*)d_out;

    (void)hipFuncSetAttribute((const void*)gnn_pool_kernel,
                              hipFuncAttributeMaxDynamicSharedMemorySize, SMEM_BYTES);

    gnn_pool_kernel<<<NGRAPH, NT, SMEM_BYTES, stream>>>(
        gx, gedge, W1, b1, p1, W2, b2, p2, W3, b3, p3,
        lW1, lb1, lW2, lb2, lW3, lb3, gout);
}

// Round 5
// 493.029 us; speedup vs baseline: 1.2656x; 1.2656x over previous
//
#include <hip/hip_runtime.h>
#include <math.h>

#define NGRAPH 1024
#define NN     256
#define NE     2048
#define EMB    39
#define HD     64
#define STRIDE 65     // bank = (row + lane) % 32 -> exactly 2-way alias on row ops = free (m136)
#define NT     512    // 8 waves; LDS 80.5KB -> 2 blocks/CU; VGPR cap 128 (no spill: ~64 live)
#define K1 205
#define K2 164
#define K3 132

// LDS (floats unless noted):
//  feat    16640  one buffer: x -> h' = dinv*h (in place) -> pooled rows
//  scratch  2048  union: epk u16[2048] bytes[0,4096) (B1-B4) | col u8[2048] bytes[4096,6144) (B4-B5)
//                        ipart i32[512] (B8-B9) | red f[1024] (B10-B12)
//  cnt 260 i ; cur 256 i ; dinv 256 f ; score 256 f (16B-aligned) ; feats 128 f
//  pn 64 ; mlp1 64 ; mlp2 32 ; nodemap 256 s16
//  total = 80528 B -> 2 blocks/CU (161056 <= 163840)
#define SMEM_BYTES 80528

struct Lds {
    float* feat; float* scratch; int* cnt; int* cur; float* dinv; float* score;
    float* feats; float* pn; float* mlp1; float* mlp2; short* nodemap;
};

template<int FIN>
__device__ __forceinline__ void layer_body(
    const Lds& S, const int* __restrict__ eb,
    const float* __restrict__ W, const float* __restrict__ bvec,
    const float* __restrict__ pvec, int n, int kkeep, int tid)
{
    unsigned short* epk   = (unsigned short*)S.scratch;          // bytes [0,4096)
    unsigned char*  col   = (unsigned char*)(S.scratch + 1024);  // bytes [4096,6144)
    int*            ipart = (int*)S.scratch;                     // aliases epk (dead)
    float*          red   = S.scratch;                           // aliases col/ipart (dead)
    const int lane = tid & 63;
    const int w    = tid >> 6;       // 0..7

    // B0: zero counts; wave0: pn = p/||p||
    if (tid < 257) S.cnt[tid] = 0;
    if (tid < 64) {
        float pv = pvec[tid];
        float s2 = pv * pv;
        #pragma unroll
        for (int off = 32; off >= 1; off >>= 1) s2 += __shfl_xor(s2, off, 64);
        S.pn[tid] = pv * rsqrtf(s2);
    }
    __syncthreads();

    // B1: remap orig edges via cumulative nodemap; int-atomic in-degree count
    for (int e = tid; e < NE; e += NT) {
        int s0 = eb[e];
        int d0 = eb[NE + e];
        int s = S.nodemap[s0];
        int d = S.nodemap[d0];
        unsigned short pk = 0xFFFFu;
        if ((s | d) >= 0) {
            pk = (unsigned short)(s | (d << 8));
            atomicAdd(&S.cnt[d], 1);          // native ds_add_u32
        }
        epk[e] = pk;
    }
    __syncthreads();

    // B2: exclusive scan cnt[0..255] -> offsets (single wave)
    if (tid < 64) {
        int base = tid * 4;
        int c0 = S.cnt[base], c1 = S.cnt[base + 1], c2 = S.cnt[base + 2], c3 = S.cnt[base + 3];
        int s4 = c0 + c1 + c2 + c3;
        int x = s4;
        #pragma unroll
        for (int off = 1; off < 64; off <<= 1) {
            int t = __shfl_up(x, off, 64);
            if (tid >= off) x += t;
        }
        int e0 = x - s4;
        S.cnt[base]     = e0;
        S.cnt[base + 1] = e0 + c0;
        S.cnt[base + 2] = e0 + c0 + c1;
        S.cnt[base + 3] = e0 + c0 + c1 + c2;
        if (tid == 63) S.cnt[256] = x;
    }
    __syncthreads();

    // B3: cursors = offsets; dinv = rsqrt(1+indeg)
    if (tid < 256) {
        int o0 = S.cnt[tid], o1 = S.cnt[tid + 1];
        S.cur[tid]  = o0;
        S.dinv[tid] = rsqrtf((float)(1 + o1 - o0));
    }
    __syncthreads();

    // B4: CSR fill (int-atomic cursors) + matmul h = x@W (2 thr/node x 32 out), store h' = dinv*h
    for (int e = tid; e < NE; e += NT) {
        unsigned pk = epk[e];
        if (pk != 0xFFFFu) {
            int d = pk >> 8;
            int pos = atomicAdd(&S.cur[d], 1);
            col[pos] = (unsigned char)(pk & 0xFFu);
        }
    }
    {
        const int nodeM = tid & 255;
        const int half = __builtin_amdgcn_readfirstlane(tid >> 8);  // wave-uniform 0/1
        float h[32];
        if (nodeM < n) {
            #pragma unroll
            for (int j = 0; j < 32; j++) h[j] = 0.f;
            const float* Wp   = W + half * 32;
            const float* xrow = S.feat + nodeM * STRIDE;
            for (int k = 0; k < FIN; k++) {
                float xv = xrow[k];
                #pragma unroll
                for (int j = 0; j < 32; j++) h[j] = fmaf(xv, Wp[k * HD + j], h[j]);
            }
        }
        __syncthreads();   // all x reads done before h' overwrites (in-place)
        if (nodeM < n) {
            float dv = S.dinv[nodeM];
            float* hrow = S.feat + nodeM * STRIDE + half * 32;
            #pragma unroll
            for (int j = 0; j < 32; j++) hrow[j] = h[j] * dv;
        }
    }
    __syncthreads();

    // B5: gather, wave-per-node (32 nodes/wave), lane=feature. 2 LDS ops/edge.
    // v[i] = relu(dvd*(sum h'_src + h'_self) + b) * tanh(score)  -- fused, only v kept live
    float v[32];
    {
        const float bl = bvec[lane];
        const float pl = S.pn[lane];
        #pragma unroll
        for (int i = 0; i < 32; i++) {
            int node = w * 32 + i;
            if (node < n) {
                int o0 = S.cnt[node], o1 = S.cnt[node + 1];   // broadcast reads
                float acc = S.feat[node * STRIDE + lane];     // h'_self
                #pragma unroll 2
                for (int e = o0; e < o1; e++) {
                    int s = col[e];                            // broadcast u8
                    acc += S.feat[s * STRIDE + lane];
                }
                float dvd = S.dinv[node];
                float o = fmaxf(fmaf(dvd, acc, bl), 0.f);
                float sc = o * pl;
                #pragma unroll
                for (int off = 32; off >= 1; off >>= 1) sc += __shfl_xor(sc, off, 64);
                float tv = tanhf(sc);
                v[i] = o * tv;
                if (lane == 0) S.score[node] = tv;
            } else {
                v[i] = 0.f;
                if (lane == 0) S.score[node] = -3.4e38f;       // -inf pad: never selected
            }
        }
    }
    __syncthreads();

    // B8: rank by counting, 2 thr/node, float4 broadcast reads over 128-score slices
    {
        const int nodeR = tid & 255;
        const int q = tid >> 8;       // 0/1
        float si = S.score[nodeR];
        const float4* s4 = (const float4*)(S.score + q * 128);
        int c = 0;
        #pragma unroll
        for (int t = 0; t < 32; t++) {
            float4 vv = s4[t];
            int j = q * 128 + t * 4;
            c += (vv.x > si) || (vv.x == si && (j    ) < nodeR);
            c += (vv.y > si) || (vv.y == si && (j + 1) < nodeR);
            c += (vv.z > si) || (vv.z == si && (j + 2) < nodeR);
            c += (vv.w > si) || (vv.w == si && (j + 3) < nodeR);
        }
        ipart[tid] = c;
    }
    __syncthreads();

    // B9: rank -> cur (cursors dead)
    if (tid < 256) S.cur[tid] = ipart[tid] + ipart[tid + 256];
    __syncthreads();

    // B10: compose nodemap; pooled rows + readout partials straight from v regs
    if (tid < 256) {
        int m = S.nodemap[tid];
        if (m >= 0) {
            int r = S.cur[m];
            S.nodemap[tid] = (short)((r < kkeep) ? r : -1);
        }
    }
    {
        float mx = -3.4e38f, sm = 0.f;
        #pragma unroll
        for (int i = 0; i < 32; i++) {
            int node = w * 32 + i;
            int r = S.cur[node];                 // wave-uniform broadcast
            if (node < n && r < kkeep) {
                S.feat[r * STRIDE + lane] = v[i];
                mx = fmaxf(mx, v[i]);
                sm += v[i];
            }
        }
        red[w * 64 + lane]       = mx;
        red[512 + w * 64 + lane] = sm;
    }
    __syncthreads();

    // B12: combine 8 wave-partials into feats
    if (tid < 64) {
        float mx = red[tid], sm = red[512 + tid];
        #pragma unroll
        for (int q = 1; q < 8; q++) {
            mx = fmaxf(mx, red[q * 64 + tid]);
            sm += red[512 + q * 64 + tid];
        }
        S.feats[tid]      += mx;
        S.feats[64 + tid] += sm / (float)kkeep;
    }
    __syncthreads();
}

__global__ __launch_bounds__(NT, 4) void gnn_pool_kernel(
    const float* __restrict__ gx, const int* __restrict__ gedge,
    const float* __restrict__ W1, const float* __restrict__ b1, const float* __restrict__ p1,
    const float* __restrict__ W2, const float* __restrict__ b2, const float* __restrict__ p2,
    const float* __restrict__ W3, const float* __restrict__ b3, const float* __restrict__ p3,
    const float* __restrict__ lW1, const float* __restrict__ lb1,
    const float* __restrict__ lW2, const float* __restrict__ lb2,
    const float* __restrict__ lW3, const float* __restrict__ lb3,
    float* __restrict__ gout)
{
    extern __shared__ __align__(16) char smem_raw[];
    Lds S;
    S.feat    = (float*)smem_raw;                 // 16640
    S.scratch = S.feat + NN * STRIDE;             // 2048
    S.cnt     = (int*)(S.scratch + 2048);         // 260
    S.cur     = S.cnt + 260;                      // 256
    S.dinv    = (float*)(S.cur + 256);            // 256
    S.score   = S.dinv + 256;                     // 256 (byte off 77840, 16B-aligned)
    S.feats   = S.score + 256;                    // 128
    S.pn      = S.feats + 128;                    // 64
    S.mlp1    = S.pn + 64;                        // 64
    S.mlp2    = S.mlp1 + 64;                      // 32
    S.nodemap = (short*)(S.mlp2 + 32);            // 256 s16

    const int tid = threadIdx.x;
    const int b   = blockIdx.x;
    const int* eb = gedge + (size_t)b * 2 * NE;

    {
        const float* xb = gx + (size_t)b * NN * EMB;
        for (int i = tid; i < NN * EMB; i += NT) {
            S.feat[(i / EMB) * STRIDE + (i % EMB)] = xb[i];
        }
        if (tid < NN) S.nodemap[tid] = (short)tid;
        if (tid < 2 * HD) S.feats[tid] = 0.f;
    }
    __syncthreads();

    layer_body<EMB>(S, eb, W1, b1, p1, NN, K1, tid);
    layer_body<HD >(S, eb, W2, b2, p2, K1, K2, tid);
    layer_body<HD >(S, eb, W3, b3, p3, K2, K3, tid);

    // final MLP: 128 -> 64 -> 32 -> 1, sigmoid
    if (tid < 64) {
        float a = lb1[tid];
        for (int i = 0; i < 2 * HD; i++) a = fmaf(S.feats[i], lW1[i * 64 + tid], a);
        S.mlp1[tid] = fmaxf(a, 0.f);
    }
    __syncthreads();
    if (tid < 32) {
        float a = lb2[tid];
        for (int i = 0; i < 64; i++) a = fmaf(S.mlp1[i], lW2[i * 32 + tid], a);
        S.mlp2[tid] = fmaxf(a, 0.f);
    }
    __syncthreads();
    if (tid == 0) {
        float a = lb3[0];
        for (int i = 0; i < 32; i++) a = fmaf(S.mlp2[i], lW3[i], a);
        gout[b] = 1.0f / (1.0f + expf(-a));
    }
}

extern "C" void kernel_launch(void* const* d_in, const int* in_sizes, int n_in,
                              void* d_out, int out_size, void* d_ws, size_t ws_size,
                              hipStream_t stream) {
    const float* gx    = (const float*)d_in[0];
    const int*   gedge = (const int*)d_in[1];
    const float* W1 = (const float*)d_in[2];
    const float* b1 = (const float*)d_in[3];
    const float* p1 = (const float*)d_in[4];
    const float* W2 = (const float*)d_in[5];
    const float* b2 = (const float*)d_in[6];
    const float* p2 = (const float*)d_in[7];
    const float* W3 = (const float*)d_in[8];
    const float* b3 = (const float*)d_in[9];
    const float* p3 = (const float*)d_in[10];
    const float* lW1 = (const float*)d_in[11];
    const float* lb1 = (const float*)d_in[12];
    const float* lW2 = (const float*)d_in[13];
    const float* lb2 = (const float*)d_in[14];
    const float* lW3 = (const float*)d_in[15];
    const float* lb3 = (const float*)d_in[16];
    float* gout = (float*)d_out;

    (void)hipFuncSetAttribute((const void*)gnn_pool_kernel,
                              hipFuncAttributeMaxDynamicSharedMemorySize, SMEM_BYTES);

    gnn_pool_kernel<<<NGRAPH, NT, SMEM_BYTES, stream>>>(
        gx, gedge, W1, b1, p1, W2, b2, p2, W3, b3, p3,
        lW1, lb1, lW2, lb2, lW3, lb3, gout);
}